// Round 5
// baseline (109.690 us; speedup 1.0000x reference)
//
#include <hip/hip_runtime.h>
#include <hip/hip_bf16.h>

typedef float f32x4 __attribute__((ext_vector_type(4)));
typedef __bf16 bf16x8 __attribute__((ext_vector_type(8)));
typedef unsigned short u16;

// Problem dims (fixed): B=128, T=64, H=1024, Hu=512, J=129, N=128, I=64, MJW=64
// ws layout
#define OFF_W1T  0u            // 512x1024 bf16 = 1048576 B  (W1T[n][k] = W1[k][n])
#define OFF_W23B 1048576u      // 144x512 bf16 in MFMA-fragment order = 147456 B
#define OFF_TS   1196032u      // 8192x512 bf16 = 8388608 B

static __device__ __forceinline__ u16 f2bf(float x) {
    __bf16 h = (__bf16)x;
    return __builtin_bit_cast(u16, h);
}

// ---------------------------------------------------------------------------
// prep: blocks 0..127 = coalesced LDS-tile transpose W1(1024x512 f32)->W1T bf16
//       blocks 128..163 = W2/W3 -> W23B in MFMA fragment order
// ---------------------------------------------------------------------------
__global__ __launch_bounds__(256) void prep_kernel(
    const float* __restrict__ W1, const float* __restrict__ W2,
    const float* __restrict__ W3,
    __bf16* __restrict__ W1T, __bf16* __restrict__ W23B)
{
    const int t = threadIdx.x;
    if (blockIdx.x < 128) {
        __shared__ __bf16 lds_t[64][72];
        const int kt = blockIdx.x >> 3, nt = blockIdx.x & 7;
        const int k0 = kt * 64, n0 = nt * 64;
        {
            const int kr = t >> 2, c0 = (t & 3) * 16;
            const float* src = W1 + (size_t)(k0 + kr) * 512 + n0 + c0;
            #pragma unroll
            for (int q = 0; q < 4; ++q) {
                float4 v = *(const float4*)(src + q * 4);
                lds_t[kr][c0 + q * 4 + 0] = (__bf16)v.x;
                lds_t[kr][c0 + q * 4 + 1] = (__bf16)v.y;
                lds_t[kr][c0 + q * 4 + 2] = (__bf16)v.z;
                lds_t[kr][c0 + q * 4 + 3] = (__bf16)v.w;
            }
        }
        __syncthreads();
        {
            const int nr = t >> 2, kc = (t & 3) * 16;
            bf16x8 o0, o1;
            #pragma unroll
            for (int j = 0; j < 8; ++j) o0[j] = lds_t[kc + j][nr];
            #pragma unroll
            for (int j = 0; j < 8; ++j) o1[j] = lds_t[kc + 8 + j][nr];
            __bf16* dst = W1T + (size_t)(n0 + nr) * 1024 + k0 + kc;
            *(bf16x8*)(dst)     = o0;
            *(bf16x8*)(dst + 8) = o1;
        }
    } else {
        int g = (blockIdx.x - 128) * 256 + t;   // 0..9215
        if (g < 9216) {
            int n = g >> 6;            // 0..143
            int k8 = (g & 63) * 8;     // 0,8,..,504
            bf16x8 v;
            #pragma unroll
            for (int j = 0; j < 8; ++j) {
                int k = k8 + j;
                float x = 0.0f;
                if (n < 129) x = W2[(size_t)k * 129 + n];
                else if (n == 129) x = W3[k];
                v[j] = (__bf16)x;
            }
            int kk = k8 >> 5, lg = (k8 >> 3) & 3, ct = n >> 4, lr = n & 15;
            *(bf16x8*)&W23B[(((size_t)(kk * 9 + ct)) * 64 + lg * 16 + lr) * 8] = v;
        }
    }
}

// ---------------------------------------------------------------------------
// GEMM1: ts = tanh(Y[8192x1024] @ W1[1024x512] + b1), bf16 MFMA 16x16x32
// 64x128 tile, BK=64, 256 threads (4 waves, wave tile 64x32), dbuf swizzled
// LDS, raw s_barrier (counted vmcnt survives barrier), 4 rolling register
// stages = depth-3 in-flight prefetch (WRITE(kt) waits vmcnt(24)).
// ---------------------------------------------------------------------------
struct StageA { float4 a0, a1, a2, a3; };    // 16 f32 of Y
struct StageB { uint4 b0, b1, b2, b3; };     // 32 bf16 of W1T

__global__ __launch_bounds__(256, 2) void gemm1_kernel(
    const float* __restrict__ Y, const __bf16* __restrict__ W1T,
    const float* __restrict__ b1, u16* __restrict__ ts)
{
    __shared__ __bf16 As[2][64 * 64];
    __shared__ __bf16 Bs[2][128 * 64];
    const int tid = threadIdx.x;
    const int m0 = blockIdx.x * 64, n0 = blockIdx.y * 128;
    const int wid = tid >> 6, lane = tid & 63;
    const int lr = lane & 15, lg = lane >> 4;

    const int ar = tid >> 2, akc = (tid & 3) * 16;
    const int asw = (ar & 7) << 3;
    const int ae0 = akc ^ asw, ae1 = (akc + 8) ^ asw;
    const int br = tid >> 1, bkc = (tid & 1) * 32;
    const int bsw = (br & 7) << 3;
    const int be0 = bkc ^ bsw, be1 = (bkc + 8) ^ bsw;
    const int be2 = (bkc + 16) ^ bsw, be3 = (bkc + 24) ^ bsw;

    const float*  ya = Y   + (size_t)(m0 + ar) * 1024 + akc;
    const __bf16* wb = W1T + (size_t)(n0 + br) * 1024 + bkc;

    f32x4 acc[4][2];
    #pragma unroll
    for (int m = 0; m < 4; m++)
        #pragma unroll
        for (int n = 0; n < 2; n++) { f32x4 z = {0.f,0.f,0.f,0.f}; acc[m][n] = z; }

#define ISSUE(SA_, SB_, kt) do { \
    const float4* yp = (const float4*)(ya + (kt) * 64); \
    (SA_).a0 = yp[0]; (SA_).a1 = yp[1]; (SA_).a2 = yp[2]; (SA_).a3 = yp[3]; \
    const uint4* wp = (const uint4*)(wb + (kt) * 64); \
    (SB_).b0 = wp[0]; (SB_).b1 = wp[1]; (SB_).b2 = wp[2]; (SB_).b3 = wp[3]; \
} while (0)

#define WRITE(SA_, SB_, buf) do { \
    bf16x8 pa0, pa1; \
    pa0[0]=(__bf16)(SA_).a0.x; pa0[1]=(__bf16)(SA_).a0.y; pa0[2]=(__bf16)(SA_).a0.z; pa0[3]=(__bf16)(SA_).a0.w; \
    pa0[4]=(__bf16)(SA_).a1.x; pa0[5]=(__bf16)(SA_).a1.y; pa0[6]=(__bf16)(SA_).a1.z; pa0[7]=(__bf16)(SA_).a1.w; \
    pa1[0]=(__bf16)(SA_).a2.x; pa1[1]=(__bf16)(SA_).a2.y; pa1[2]=(__bf16)(SA_).a2.z; pa1[3]=(__bf16)(SA_).a2.w; \
    pa1[4]=(__bf16)(SA_).a3.x; pa1[5]=(__bf16)(SA_).a3.y; pa1[6]=(__bf16)(SA_).a3.z; pa1[7]=(__bf16)(SA_).a3.w; \
    *(bf16x8*)&As[buf][ar * 64 + ae0] = pa0; \
    *(bf16x8*)&As[buf][ar * 64 + ae1] = pa1; \
    *(uint4*)&Bs[buf][br * 64 + be0] = (SB_).b0; \
    *(uint4*)&Bs[buf][br * 64 + be1] = (SB_).b1; \
    *(uint4*)&Bs[buf][br * 64 + be2] = (SB_).b2; \
    *(uint4*)&Bs[buf][br * 64 + be3] = (SB_).b3; \
} while (0)

#define BARRIER() do { \
    asm volatile("s_waitcnt lgkmcnt(0)" ::: "memory"); \
    __builtin_amdgcn_s_barrier(); \
} while (0)

#define COMPUTE(buf) do { \
    const int swl = (lr & 7) << 3; \
    _Pragma("unroll") \
    for (int ks = 0; ks < 2; ++ks) { \
        const int eoff = (ks * 32 + lg * 8) ^ swl; \
        bf16x8 af[4], bfr[2]; \
        _Pragma("unroll") \
        for (int m = 0; m < 4; ++m) af[m] = *(const bf16x8*)&As[buf][(m * 16 + lr) * 64 + eoff]; \
        _Pragma("unroll") \
        for (int n = 0; n < 2; ++n) bfr[n] = *(const bf16x8*)&Bs[buf][(wid * 32 + n * 16 + lr) * 64 + eoff]; \
        __builtin_amdgcn_s_setprio(1); \
        _Pragma("unroll") \
        for (int m = 0; m < 4; ++m) \
            _Pragma("unroll") \
            for (int n = 0; n < 2; ++n) \
                acc[m][n] = __builtin_amdgcn_mfma_f32_16x16x32_bf16(af[m], bfr[n], acc[m][n], 0, 0, 0); \
        __builtin_amdgcn_s_setprio(0); \
    } \
} while (0)

    StageA A0, A1, A2, A3; StageB B0, B1, B2, B3;
    ISSUE(A0, B0, 0); ISSUE(A1, B1, 1); ISSUE(A2, B2, 2);
    #pragma unroll 1
    for (int kt = 0; kt < 16; kt += 4) {
        WRITE(A0, B0, 0); if (kt + 3 < 16) ISSUE(A3, B3, kt + 3);
        BARRIER(); COMPUTE(0);
        WRITE(A1, B1, 1); if (kt + 4 < 16) ISSUE(A0, B0, kt + 4);
        BARRIER(); COMPUTE(1);
        WRITE(A2, B2, 0); if (kt + 5 < 16) ISSUE(A1, B1, kt + 5);
        BARRIER(); COMPUTE(0);
        WRITE(A3, B3, 1); if (kt + 6 < 16) ISSUE(A2, B2, kt + 6);
        BARRIER(); COMPUTE(1);
    }

    // epilogue: bias + tanh + bf16 store
    #pragma unroll
    for (int m = 0; m < 4; m++) {
        #pragma unroll
        for (int n = 0; n < 2; n++) {
            int col = n0 + wid * 32 + n * 16 + lr;
            float bias = b1[col];
            #pragma unroll
            for (int j = 0; j < 4; j++) {
                int row = m0 + m * 16 + lg * 4 + j;
                float v = tanhf(acc[m][n][j] + bias);
                ts[(size_t)row * 512 + col] = f2bf(v);
            }
        }
    }
#undef ISSUE
#undef WRITE
#undef BARRIER
#undef COMPUTE
}

// ---------------------------------------------------------------------------
// FUSED gemm2 + softmax + sigmoid + recurrence. One block = one batch.
// Softmax writes the band TRANSPOSED: jwT_s[c][k] = M[k][c] (pad 65 ->
// conflict-free scatter and conflict-free row reads). Wave 0 then runs the
// 63-step recurrence: band column in 64 VGPRs; per iter one ds_write of
// atil + 16 uniform-address ds_read_b128 broadcasts + 64 FMA. No barriers.
// ---------------------------------------------------------------------------
__global__ __launch_bounds__(256) void gemm2_recur_kernel(
    const u16* __restrict__ ts, const u16* __restrict__ W23B,
    const float* __restrict__ b2, const float* __restrict__ b3,
    const float* __restrict__ em, const int* __restrict__ slen,
    float* __restrict__ out)
{
    __shared__ float jwT_s[64][65];   // [c][k] = M[k][c]
    __shared__ float em_s[128][65];
    __shared__ float p0_s[64];
    __shared__ float a_bc[64];
    const int b = blockIdx.x;
    const int tid = threadIdx.x;
    const int w = tid >> 6, lane = tid & 63;
    const int lr = lane & 15, lg = lane >> 4;
    const int r0 = b * 64 + w * 16;

    // stage emission (independent of the GEMM; overlaps it)
    {
        const float4* eg = (const float4*)(em + (size_t)b * 8192);
        #pragma unroll
        for (int q = 0; q < 8; ++q) {
            int i4 = tid + q * 256;
            float4 v = eg[i4];
            int base = i4 * 4; int n = base >> 6; int ii = base & 63;
            em_s[n][ii] = v.x; em_s[n][ii + 1] = v.y; em_s[n][ii + 2] = v.z; em_s[n][ii + 3] = v.w;
        }
    }

    f32x4 acc[9];
    #pragma unroll
    for (int ct = 0; ct < 9; ct++) { f32x4 z = {0.f,0.f,0.f,0.f}; acc[ct] = z; }

    #pragma unroll 4
    for (int kk = 0; kk < 16; ++kk) {
        bf16x8 a = *(const bf16x8*)(ts + (size_t)(r0 + lr) * 512 + kk * 32 + lg * 8);
        #pragma unroll
        for (int ct = 0; ct < 9; ct++) {
            bf16x8 bv = *(const bf16x8*)(W23B + ((size_t)(kk * 9 + ct) * 64 + lane) * 8);
            acc[ct] = __builtin_amdgcn_mfma_f32_16x16x32_bf16(a, bv, acc[ct], 0, 0, 0);
        }
    }

    float b3v = b3[0];
    #pragma unroll
    for (int j = 0; j < 4; j++) {
        int rloc = w * 16 + lg * 4 + j;   // row within batch (0..63)
        float v[9];
        float mx = -1e30f;
        #pragma unroll
        for (int ct = 0; ct < 9; ct++) {
            int col = ct * 16 + lr;
            if (col < 129) { float x = acc[ct][j] + b2[col]; v[ct] = x; mx = fmaxf(mx, x); }
            else v[ct] = -1e30f;
        }
        #pragma unroll
        for (int o = 1; o < 16; o <<= 1) mx = fmaxf(mx, __shfl_xor(mx, o));
        float sum = 0.f;
        #pragma unroll
        for (int ct = 0; ct < 9; ct++) {
            int col = ct * 16 + lr;
            if (col < 129) { float e = expf(v[ct] - mx); v[ct] = e; sum += e; }
        }
        #pragma unroll
        for (int o = 1; o < 16; o <<= 1) sum += __shfl_xor(sum, o);
        float inv = 1.0f / sum;
        #pragma unroll
        for (int ct = 0; ct < 9; ct++) {
            int col = ct * 16 + lr;
            int cc = col - 64 + rloc;
            if (col < 129 && cc >= 0 && cc < 64)
                jwT_s[cc][rloc] = v[ct] * inv;   // transposed band write
        }
        if (lr == 1) {  // col 129 = p0 logit
            float pv = acc[8][j] + b3v;
            p0_s[rloc] = 1.0f / (1.0f + expf(-pv));
        }
    }
    __syncthreads();
    if (tid >= 64) return;

    // ---- recurrence, wave 0 only ----
    const int c = tid;
    float breg[64];
    #pragma unroll
    for (int q = 0; q < 16; ++q)
        *(float4*)&breg[q * 4] = *(const float4*)&jwT_s[c][q * 4];   // row read, conflict-free
    const float p0r = p0_s[c];
    const int idx = slen[b] - 1;

    float ut = em_s[c][0] + em_s[c + 64][0];   // atil_0
    float Lacc = 0.f;   // sum of log2(r) at rescale points

    #pragma unroll 1
    for (int i = 1; i <= idx; ++i) {
        a_bc[c] = ut;                 // per-lane ds_write
        float aloc = ut;              // diagonal-term source
        asm volatile("s_waitcnt lgkmcnt(0)" ::: "memory");
        float s0 = 0.f, s1 = 0.f, s2 = 0.f, s3 = 0.f;
        #pragma unroll
        for (int q = 0; q < 16; ++q) {
            float4 av = *(const float4*)&a_bc[q * 4];   // uniform-addr broadcast
            s0 = fmaf(av.x, breg[q * 4 + 0], s0);
            s1 = fmaf(av.y, breg[q * 4 + 1], s1);
            s2 = fmaf(av.z, breg[q * 4 + 2], s2);
            s3 = fmaf(av.w, breg[q * 4 + 3], s3);
        }
        ut = ((s0 + s1) + (s2 + s3)) * em_s[c][i] + aloc * p0r * em_s[c + 64][i];
        if (((i & 3) == 0) || (i == idx)) {
            float r = ut;
            #pragma unroll
            for (int o = 1; o < 64; o <<= 1) r += __shfl_xor(r, o);
            Lacc += __log2f(r);
            ut *= __builtin_amdgcn_rcpf(r);
        }
    }
    if (c == 0) out[b] = 1.0f + 0.6931471805599453f * (Lacc + 7.0f * (float)idx);
}

extern "C" void kernel_launch(void* const* d_in, const int* in_sizes, int n_in,
                              void* d_out, int out_size, void* d_ws, size_t ws_size,
                              hipStream_t stream)
{
    const float* Y   = (const float*)d_in[0];
    const float* em  = (const float*)d_in[1];
    const int*   sl  = (const int*)d_in[2];
    const float* W1  = (const float*)d_in[3];
    const float* b1  = (const float*)d_in[4];
    const float* W2  = (const float*)d_in[5];
    const float* b2  = (const float*)d_in[6];
    const float* W3  = (const float*)d_in[7];
    const float* b3  = (const float*)d_in[8];
    float* out = (float*)d_out;
    char* ws = (char*)d_ws;

    __bf16* W1T  = (__bf16*)(ws + OFF_W1T);
    __bf16* W23B = (__bf16*)(ws + OFF_W23B);
    u16*    ts   = (u16*)(ws + OFF_TS);

    prep_kernel<<<164, 256, 0, stream>>>(W1, W2, W3, W1T, W23B);
    dim3 g1(128, 4);
    gemm1_kernel<<<g1, 256, 0, stream>>>(Y, W1T, b1, ts);
    gemm2_recur_kernel<<<128, 256, 0, stream>>>(ts, (const u16*)W23B, b2, b3, em, sl, out);
}

// Round 6
// 87.056 us; speedup vs baseline: 1.2600x; 1.2600x over previous
//
#include <hip/hip_runtime.h>
#include <hip/hip_bf16.h>

typedef float f32x4 __attribute__((ext_vector_type(4)));
typedef __bf16 bf16x8 __attribute__((ext_vector_type(8)));
typedef unsigned short u16;

// Problem dims (fixed): B=128, T=64, H=1024, Hu=512, J=129, N=128, I=64, MJW=64
// ws layout
#define OFF_W1T  0u            // 512x1024 bf16 = 1048576 B  (W1T[n][k] = W1[k][n])
#define OFF_W23B 1048576u      // 144x512 bf16 in MFMA-fragment order = 147456 B
#define OFF_TS   1196032u      // 8192x512 bf16 = 8388608 B

static __device__ __forceinline__ u16 f2bf(float x) {
    __bf16 h = (__bf16)x;
    return __builtin_bit_cast(u16, h);
}

__device__ __forceinline__ void gload16(const void* g, void* l) {
    __builtin_amdgcn_global_load_lds(
        (const __attribute__((address_space(1))) void*)g,
        (__attribute__((address_space(3))) void*)l,
        16, 0, 0);
}

// ---------------------------------------------------------------------------
// prep: blocks 0..127 = coalesced LDS-tile transpose W1(1024x512 f32)->W1T bf16
//       blocks 128..163 = W2/W3 -> W23B in MFMA fragment order
// ---------------------------------------------------------------------------
__global__ __launch_bounds__(256) void prep_kernel(
    const float* __restrict__ W1, const float* __restrict__ W2,
    const float* __restrict__ W3,
    __bf16* __restrict__ W1T, __bf16* __restrict__ W23B)
{
    const int t = threadIdx.x;
    if (blockIdx.x < 128) {
        __shared__ __bf16 lds_t[64][72];
        const int kt = blockIdx.x >> 3, nt = blockIdx.x & 7;
        const int k0 = kt * 64, n0 = nt * 64;
        {
            const int kr = t >> 2, c0 = (t & 3) * 16;
            const float* src = W1 + (size_t)(k0 + kr) * 512 + n0 + c0;
            #pragma unroll
            for (int q = 0; q < 4; ++q) {
                float4 v = *(const float4*)(src + q * 4);
                lds_t[kr][c0 + q * 4 + 0] = (__bf16)v.x;
                lds_t[kr][c0 + q * 4 + 1] = (__bf16)v.y;
                lds_t[kr][c0 + q * 4 + 2] = (__bf16)v.z;
                lds_t[kr][c0 + q * 4 + 3] = (__bf16)v.w;
            }
        }
        __syncthreads();
        {
            const int nr = t >> 2, kc = (t & 3) * 16;
            bf16x8 o0, o1;
            #pragma unroll
            for (int j = 0; j < 8; ++j) o0[j] = lds_t[kc + j][nr];
            #pragma unroll
            for (int j = 0; j < 8; ++j) o1[j] = lds_t[kc + 8 + j][nr];
            __bf16* dst = W1T + (size_t)(n0 + nr) * 1024 + k0 + kc;
            *(bf16x8*)(dst)     = o0;
            *(bf16x8*)(dst + 8) = o1;
        }
    } else {
        int g = (blockIdx.x - 128) * 256 + t;   // 0..9215
        if (g < 9216) {
            int n = g >> 6;            // 0..143
            int k8 = (g & 63) * 8;     // 0,8,..,504
            bf16x8 v;
            #pragma unroll
            for (int j = 0; j < 8; ++j) {
                int k = k8 + j;
                float x = 0.0f;
                if (n < 129) x = W2[(size_t)k * 129 + n];
                else if (n == 129) x = W3[k];
                v[j] = (__bf16)x;
            }
            int kk = k8 >> 5, lg = (k8 >> 3) & 3, ct = n >> 4, lr = n & 15;
            *(bf16x8*)&W23B[(((size_t)(kk * 9 + ct)) * 64 + lg * 16 + lr) * 8] = v;
        }
    }
}

// ---------------------------------------------------------------------------
// GEMM1: ts = tanh(Y[8192x1024] @ W1[1024x512] + b1), bf16 MFMA 16x16x32
// Tile 64x128, BK=32, 256 thr (4 waves 2x2, wave tile 32x64).
// global_load_lds (16B) into a 3-deep LDS ring; counted vmcnt(8); raw
// barriers. A stays f32 in LDS (cvt->bf16 at fragment load). XOR-swizzled
// via pre-swizzled GLOBAL source + swizzled ds_read (T21 both-sides).
// ---------------------------------------------------------------------------
__global__ __launch_bounds__(256, 2) void gemm1_kernel(
    const float* __restrict__ Y, const __bf16* __restrict__ W1T,
    const float* __restrict__ b1, u16* __restrict__ ts)
{
    __shared__ float  As[3][64 * 32];    // f32 [64 rows][32 k], 8KB/buf
    __shared__ __bf16 Bs[3][128 * 32];   // bf16 [128 rows][32 k], 8KB/buf
    const int tid = threadIdx.x;
    const int m0 = blockIdx.x * 64, n0 = blockIdx.y * 128;
    const int wid = tid >> 6, lane = tid & 63;
    const int wr = wid >> 1, wc = wid & 1;
    const int lr = lane & 15, lg = lane >> 4;

    // staging global pointers (source pre-swizzled so linear LDS + swizzled
    // read line up; swizzle: 16B-unit u holds data-unit u ^ (row & mask))
    const int al = lane >> 3;            // A sub-row within KB (also row&7)
    const int au = (lane & 7) ^ al;      // A data unit
    const float* yA0 = Y + (size_t)(m0 + (wid * 2 + 0) * 8 + al) * 1024 + au * 4;
    const float* yA1 = Y + (size_t)(m0 + (wid * 2 + 1) * 8 + al) * 1024 + au * 4;
    const int bl = lane >> 2;            // B sub-row within KB
    const int bu = (lane & 3) ^ (bl & 3);
    const __bf16* wB0 = W1T + (size_t)(n0 + (wid * 2 + 0) * 16 + bl) * 1024 + bu * 8;
    const __bf16* wB1 = W1T + (size_t)(n0 + (wid * 2 + 1) * 16 + bl) * 1024 + bu * 8;

    f32x4 acc[2][4];
    #pragma unroll
    for (int m = 0; m < 2; m++)
        #pragma unroll
        for (int n = 0; n < 4; n++) { f32x4 z = {0.f,0.f,0.f,0.f}; acc[m][n] = z; }

#define STAGE(buf, kt) do { \
    gload16(yA0 + (kt) * 32, &As[buf][(wid * 2 + 0) * 256]); \
    gload16(yA1 + (kt) * 32, &As[buf][(wid * 2 + 1) * 256]); \
    gload16(wB0 + (kt) * 32, &Bs[buf][(wid * 2 + 0) * 512]); \
    gload16(wB1 + (kt) * 32, &Bs[buf][(wid * 2 + 1) * 512]); \
} while (0)

#define COMPUTE(buf) do { \
    bf16x8 af[2]; bf16x8 bfr[4]; \
    _Pragma("unroll") \
    for (int m = 0; m < 2; ++m) { \
        const int row = wr * 32 + m * 16 + lr; \
        const int r7 = row & 7; \
        float4 h0 = *(const float4*)&As[buf][row * 32 + (((lg * 2 + 0) ^ r7) * 4)]; \
        float4 h1 = *(const float4*)&As[buf][row * 32 + (((lg * 2 + 1) ^ r7) * 4)]; \
        bf16x8 tt; \
        tt[0]=(__bf16)h0.x; tt[1]=(__bf16)h0.y; tt[2]=(__bf16)h0.z; tt[3]=(__bf16)h0.w; \
        tt[4]=(__bf16)h1.x; tt[5]=(__bf16)h1.y; tt[6]=(__bf16)h1.z; tt[7]=(__bf16)h1.w; \
        af[m] = tt; \
    } \
    _Pragma("unroll") \
    for (int n = 0; n < 4; ++n) { \
        const int rowb = wc * 64 + n * 16 + lr; \
        bfr[n] = *(const bf16x8*)&Bs[buf][rowb * 32 + ((lg ^ (rowb & 3)) * 8)]; \
    } \
    __builtin_amdgcn_s_setprio(1); \
    _Pragma("unroll") \
    for (int m = 0; m < 2; ++m) \
        _Pragma("unroll") \
        for (int n = 0; n < 4; ++n) \
            acc[m][n] = __builtin_amdgcn_mfma_f32_16x16x32_bf16(af[m], bfr[n], acc[m][n], 0, 0, 0); \
    __builtin_amdgcn_s_setprio(0); \
} while (0)

#define KSTEP(buf, kt, VM, DO_STAGE) do { \
    asm volatile("s_waitcnt vmcnt(" #VM ")" ::: "memory"); \
    __builtin_amdgcn_s_barrier(); \
    COMPUTE(buf); \
    asm volatile("s_waitcnt lgkmcnt(0)" ::: "memory"); \
    __builtin_amdgcn_s_barrier(); \
    if (DO_STAGE) STAGE(buf, (kt) + 3); \
} while (0)

    STAGE(0, 0); STAGE(1, 1); STAGE(2, 2);
    #pragma unroll 1
    for (int base = 0; base < 27; base += 3) {
        KSTEP(0, base + 0, 8, 1);
        KSTEP(1, base + 1, 8, 1);
        KSTEP(2, base + 2, 8, 1);
    }
    KSTEP(0, 27, 8, 1);   // stages kt=30 -> buf 0
    KSTEP(1, 28, 8, 1);   // stages kt=31 -> buf 1
    KSTEP(2, 29, 8, 0);
    KSTEP(0, 30, 4, 0);
    KSTEP(1, 31, 0, 0);

    // epilogue: bias + tanh + bf16 store
    #pragma unroll
    for (int m = 0; m < 2; m++) {
        #pragma unroll
        for (int n = 0; n < 4; n++) {
            int col = n0 + wc * 64 + n * 16 + lr;
            float bias = b1[col];
            #pragma unroll
            for (int j = 0; j < 4; j++) {
                int row = m0 + wr * 32 + m * 16 + lg * 4 + j;
                float v = tanhf(acc[m][n][j] + bias);
                ts[(size_t)row * 512 + col] = f2bf(v);
            }
        }
    }
#undef STAGE
#undef COMPUTE
#undef KSTEP
}

// ---------------------------------------------------------------------------
// FUSED gemm2 + softmax + sigmoid + recurrence. One block = one batch.
// Band stored transposed in LDS (jwT_s[c][k], pad 65). Recurrence (wave 0):
// band column in f32x4 bregv[16] -- ALL indices compile-time so it promotes
// to VGPRs (round-4/5 had it in scratch: VGPR_Count 68 < 64 floats).
// Per iter: 1 ds_write + 16 uniform-addr ds_read_b128 broadcasts + 64 FMA.
// ---------------------------------------------------------------------------
__global__ __launch_bounds__(256) void gemm2_recur_kernel(
    const u16* __restrict__ ts, const u16* __restrict__ W23B,
    const float* __restrict__ b2, const float* __restrict__ b3,
    const float* __restrict__ em, const int* __restrict__ slen,
    float* __restrict__ out)
{
    __shared__ float jwT_s[64][65];   // [c][k] = M[k][c]
    __shared__ float em_s[128][65];
    __shared__ float p0_s[64];
    __shared__ float a_bc[64];
    const int b = blockIdx.x;
    const int tid = threadIdx.x;
    const int w = tid >> 6, lane = tid & 63;
    const int lr = lane & 15, lg = lane >> 4;
    const int r0 = b * 64 + w * 16;

    // stage emission (independent of the GEMM; overlaps it)
    {
        const float4* eg = (const float4*)(em + (size_t)b * 8192);
        #pragma unroll
        for (int q = 0; q < 8; ++q) {
            int i4 = tid + q * 256;
            float4 v = eg[i4];
            int base = i4 * 4; int n = base >> 6; int ii = base & 63;
            em_s[n][ii] = v.x; em_s[n][ii + 1] = v.y; em_s[n][ii + 2] = v.z; em_s[n][ii + 3] = v.w;
        }
    }

    f32x4 acc[9];
    #pragma unroll
    for (int ct = 0; ct < 9; ct++) { f32x4 z = {0.f,0.f,0.f,0.f}; acc[ct] = z; }

    #pragma unroll 4
    for (int kk = 0; kk < 16; ++kk) {
        bf16x8 a = *(const bf16x8*)(ts + (size_t)(r0 + lr) * 512 + kk * 32 + lg * 8);
        #pragma unroll
        for (int ct = 0; ct < 9; ct++) {
            bf16x8 bv = *(const bf16x8*)(W23B + ((size_t)(kk * 9 + ct) * 64 + lane) * 8);
            acc[ct] = __builtin_amdgcn_mfma_f32_16x16x32_bf16(a, bv, acc[ct], 0, 0, 0);
        }
    }

    float b3v = b3[0];
    #pragma unroll
    for (int j = 0; j < 4; j++) {
        int rloc = w * 16 + lg * 4 + j;   // row within batch (0..63)
        float v[9];
        float mx = -1e30f;
        #pragma unroll
        for (int ct = 0; ct < 9; ct++) {
            int col = ct * 16 + lr;
            if (col < 129) { float x = acc[ct][j] + b2[col]; v[ct] = x; mx = fmaxf(mx, x); }
            else v[ct] = -1e30f;
        }
        #pragma unroll
        for (int o = 1; o < 16; o <<= 1) mx = fmaxf(mx, __shfl_xor(mx, o));
        float sum = 0.f;
        #pragma unroll
        for (int ct = 0; ct < 9; ct++) {
            int col = ct * 16 + lr;
            if (col < 129) { float e = expf(v[ct] - mx); v[ct] = e; sum += e; }
        }
        #pragma unroll
        for (int o = 1; o < 16; o <<= 1) sum += __shfl_xor(sum, o);
        float inv = 1.0f / sum;
        #pragma unroll
        for (int ct = 0; ct < 9; ct++) {
            int col = ct * 16 + lr;
            int cc = col - 64 + rloc;
            if (col < 129 && cc >= 0 && cc < 64)
                jwT_s[cc][rloc] = v[ct] * inv;   // transposed band write
        }
        if (lr == 1) {  // col 129 = p0 logit
            float pv = acc[8][j] + b3v;
            p0_s[rloc] = 1.0f / (1.0f + expf(-pv));
        }
    }
    __syncthreads();
    if (tid >= 64) return;

    // ---- recurrence, wave 0 only ----
    const int c = tid;
    f32x4 bregv[16];                    // constant-indexed only -> VGPRs
    #pragma unroll
    for (int q = 0; q < 16; ++q)
        bregv[q] = *(const f32x4*)&jwT_s[c][q * 4];   // row read, conflict-free
    const float p0r = p0_s[c];
    const int idx = slen[b] - 1;

    float ut = em_s[c][0] + em_s[c + 64][0];   // atil_0
    float Lacc = 0.f;   // sum of log2(r) at rescale points

    #pragma unroll 1
    for (int i = 1; i <= idx; ++i) {
        a_bc[c] = ut;                 // per-lane ds_write
        float aloc = ut;              // diagonal-term source
        asm volatile("s_waitcnt lgkmcnt(0)" ::: "memory");
        float s0 = 0.f, s1 = 0.f, s2 = 0.f, s3 = 0.f;
        #pragma unroll
        for (int q = 0; q < 16; ++q) {
            float4 av = *(const float4*)&a_bc[q * 4];   // uniform-addr broadcast
            s0 = fmaf(av.x, bregv[q][0], s0);
            s1 = fmaf(av.y, bregv[q][1], s1);
            s2 = fmaf(av.z, bregv[q][2], s2);
            s3 = fmaf(av.w, bregv[q][3], s3);
        }
        ut = ((s0 + s1) + (s2 + s3)) * em_s[c][i] + aloc * p0r * em_s[c + 64][i];
        if (((i & 3) == 0) || (i == idx)) {
            float r = ut;
            #pragma unroll
            for (int o = 1; o < 64; o <<= 1) r += __shfl_xor(r, o);
            Lacc += __log2f(r);
            ut *= __builtin_amdgcn_rcpf(r);
        }
    }
    if (c == 0) out[b] = 1.0f + 0.6931471805599453f * (Lacc + 7.0f * (float)idx);
}

extern "C" void kernel_launch(void* const* d_in, const int* in_sizes, int n_in,
                              void* d_out, int out_size, void* d_ws, size_t ws_size,
                              hipStream_t stream)
{
    const float* Y   = (const float*)d_in[0];
    const float* em  = (const float*)d_in[1];
    const int*   sl  = (const int*)d_in[2];
    const float* W1  = (const float*)d_in[3];
    const float* b1  = (const float*)d_in[4];
    const float* W2  = (const float*)d_in[5];
    const float* b2  = (const float*)d_in[6];
    const float* W3  = (const float*)d_in[7];
    const float* b3  = (const float*)d_in[8];
    float* out = (float*)d_out;
    char* ws = (char*)d_ws;

    __bf16* W1T  = (__bf16*)(ws + OFF_W1T);
    __bf16* W23B = (__bf16*)(ws + OFF_W23B);
    u16*    ts   = (u16*)(ws + OFF_TS);

    prep_kernel<<<164, 256, 0, stream>>>(W1, W2, W3, W1T, W23B);
    dim3 g1(128, 4);
    gemm1_kernel<<<g1, 256, 0, stream>>>(Y, W1T, b1, ts);
    gemm2_recur_kernel<<<128, 256, 0, stream>>>(ts, (const u16*)W23B, b2, b3, em, sl, out);
}

// Round 7
// 82.744 us; speedup vs baseline: 1.3257x; 1.0521x over previous
//
#include <hip/hip_runtime.h>
#include <hip/hip_bf16.h>

typedef float f32x4 __attribute__((ext_vector_type(4)));
typedef __bf16 bf16x8 __attribute__((ext_vector_type(8)));
typedef unsigned short u16;

// Problem dims (fixed): B=128, T=64, H=1024, Hu=512, J=129, N=128, I=64, MJW=64
// ws layout
#define OFF_W1T  0u            // 512x1024 bf16 = 1048576 B  (W1T[n][k] = W1[k][n])
#define OFF_W23B 1048576u      // 144x512 bf16 in MFMA-fragment order = 147456 B
#define OFF_TS   1196032u      // 8192x512 bf16 = 8388608 B

static __device__ __forceinline__ u16 f2bf(float x) {
    __bf16 h = (__bf16)x;
    return __builtin_bit_cast(u16, h);
}

__device__ __forceinline__ void gload16(const void* g, void* l) {
    __builtin_amdgcn_global_load_lds(
        (const __attribute__((address_space(1))) void*)g,
        (__attribute__((address_space(3))) void*)l,
        16, 0, 0);
}

// ---------------------------------------------------------------------------
// prep: blocks 0..127 = coalesced LDS-tile transpose W1(1024x512 f32)->W1T bf16
//       blocks 128..163 = W2/W3 -> W23B in MFMA fragment order
// ---------------------------------------------------------------------------
__global__ __launch_bounds__(256) void prep_kernel(
    const float* __restrict__ W1, const float* __restrict__ W2,
    const float* __restrict__ W3,
    __bf16* __restrict__ W1T, __bf16* __restrict__ W23B)
{
    const int t = threadIdx.x;
    if (blockIdx.x < 128) {
        __shared__ __bf16 lds_t[64][72];
        const int kt = blockIdx.x >> 3, nt = blockIdx.x & 7;
        const int k0 = kt * 64, n0 = nt * 64;
        {
            const int kr = t >> 2, c0 = (t & 3) * 16;
            const float* src = W1 + (size_t)(k0 + kr) * 512 + n0 + c0;
            #pragma unroll
            for (int q = 0; q < 4; ++q) {
                float4 v = *(const float4*)(src + q * 4);
                lds_t[kr][c0 + q * 4 + 0] = (__bf16)v.x;
                lds_t[kr][c0 + q * 4 + 1] = (__bf16)v.y;
                lds_t[kr][c0 + q * 4 + 2] = (__bf16)v.z;
                lds_t[kr][c0 + q * 4 + 3] = (__bf16)v.w;
            }
        }
        __syncthreads();
        {
            const int nr = t >> 2, kc = (t & 3) * 16;
            bf16x8 o0, o1;
            #pragma unroll
            for (int j = 0; j < 8; ++j) o0[j] = lds_t[kc + j][nr];
            #pragma unroll
            for (int j = 0; j < 8; ++j) o1[j] = lds_t[kc + 8 + j][nr];
            __bf16* dst = W1T + (size_t)(n0 + nr) * 1024 + k0 + kc;
            *(bf16x8*)(dst)     = o0;
            *(bf16x8*)(dst + 8) = o1;
        }
    } else {
        int g = (blockIdx.x - 128) * 256 + t;   // 0..9215
        if (g < 9216) {
            int n = g >> 6;            // 0..143
            int k8 = (g & 63) * 8;     // 0,8,..,504
            bf16x8 v;
            #pragma unroll
            for (int j = 0; j < 8; ++j) {
                int k = k8 + j;
                float x = 0.0f;
                if (n < 129) x = W2[(size_t)k * 129 + n];
                else if (n == 129) x = W3[k];
                v[j] = (__bf16)x;
            }
            int kk = k8 >> 5, lg = (k8 >> 3) & 3, ct = n >> 4, lr = n & 15;
            *(bf16x8*)&W23B[(((size_t)(kk * 9 + ct)) * 64 + lg * 16 + lr) * 8] = v;
        }
    }
}

// ---------------------------------------------------------------------------
// GEMM1: ts = tanh(Y[8192x1024] @ W1[1024x512] + b1), bf16 MFMA 16x16x32
// Tile 64x128, BK=32, 256 thr (4 waves 2x2, wave tile 32x64).
// global_load_lds (16B) into a 3-deep LDS ring; counted vmcnt(8); raw
// barriers. A stays f32 in LDS (cvt->bf16 at fragment load). XOR-swizzled
// via pre-swizzled GLOBAL source + swizzled ds_read (T21 both-sides).
// (unchanged from round 6 -- known-good; its true cost surfaces next round)
// ---------------------------------------------------------------------------
__global__ __launch_bounds__(256, 2) void gemm1_kernel(
    const float* __restrict__ Y, const __bf16* __restrict__ W1T,
    const float* __restrict__ b1, u16* __restrict__ ts)
{
    __shared__ float  As[3][64 * 32];    // f32 [64 rows][32 k], 8KB/buf
    __shared__ __bf16 Bs[3][128 * 32];   // bf16 [128 rows][32 k], 8KB/buf
    const int tid = threadIdx.x;
    const int m0 = blockIdx.x * 64, n0 = blockIdx.y * 128;
    const int wid = tid >> 6, lane = tid & 63;
    const int wr = wid >> 1, wc = wid & 1;
    const int lr = lane & 15, lg = lane >> 4;

    const int al = lane >> 3;            // A sub-row within KB (also row&7)
    const int au = (lane & 7) ^ al;      // A data unit
    const float* yA0 = Y + (size_t)(m0 + (wid * 2 + 0) * 8 + al) * 1024 + au * 4;
    const float* yA1 = Y + (size_t)(m0 + (wid * 2 + 1) * 8 + al) * 1024 + au * 4;
    const int bl = lane >> 2;            // B sub-row within KB
    const int bu = (lane & 3) ^ (bl & 3);
    const __bf16* wB0 = W1T + (size_t)(n0 + (wid * 2 + 0) * 16 + bl) * 1024 + bu * 8;
    const __bf16* wB1 = W1T + (size_t)(n0 + (wid * 2 + 1) * 16 + bl) * 1024 + bu * 8;

    f32x4 acc[2][4];
    #pragma unroll
    for (int m = 0; m < 2; m++)
        #pragma unroll
        for (int n = 0; n < 4; n++) { f32x4 z = {0.f,0.f,0.f,0.f}; acc[m][n] = z; }

#define STAGE(buf, kt) do { \
    gload16(yA0 + (kt) * 32, &As[buf][(wid * 2 + 0) * 256]); \
    gload16(yA1 + (kt) * 32, &As[buf][(wid * 2 + 1) * 256]); \
    gload16(wB0 + (kt) * 32, &Bs[buf][(wid * 2 + 0) * 512]); \
    gload16(wB1 + (kt) * 32, &Bs[buf][(wid * 2 + 1) * 512]); \
} while (0)

#define COMPUTE(buf) do { \
    bf16x8 af[2]; bf16x8 bfr[4]; \
    _Pragma("unroll") \
    for (int m = 0; m < 2; ++m) { \
        const int row = wr * 32 + m * 16 + lr; \
        const int r7 = row & 7; \
        float4 h0 = *(const float4*)&As[buf][row * 32 + (((lg * 2 + 0) ^ r7) * 4)]; \
        float4 h1 = *(const float4*)&As[buf][row * 32 + (((lg * 2 + 1) ^ r7) * 4)]; \
        bf16x8 tt; \
        tt[0]=(__bf16)h0.x; tt[1]=(__bf16)h0.y; tt[2]=(__bf16)h0.z; tt[3]=(__bf16)h0.w; \
        tt[4]=(__bf16)h1.x; tt[5]=(__bf16)h1.y; tt[6]=(__bf16)h1.z; tt[7]=(__bf16)h1.w; \
        af[m] = tt; \
    } \
    _Pragma("unroll") \
    for (int n = 0; n < 4; ++n) { \
        const int rowb = wc * 64 + n * 16 + lr; \
        bfr[n] = *(const bf16x8*)&Bs[buf][rowb * 32 + ((lg ^ (rowb & 3)) * 8)]; \
    } \
    __builtin_amdgcn_s_setprio(1); \
    _Pragma("unroll") \
    for (int m = 0; m < 2; ++m) \
        _Pragma("unroll") \
        for (int n = 0; n < 4; ++n) \
            acc[m][n] = __builtin_amdgcn_mfma_f32_16x16x32_bf16(af[m], bfr[n], acc[m][n], 0, 0, 0); \
    __builtin_amdgcn_s_setprio(0); \
} while (0)

#define KSTEP(buf, kt, VM, DO_STAGE) do { \
    asm volatile("s_waitcnt vmcnt(" #VM ")" ::: "memory"); \
    __builtin_amdgcn_s_barrier(); \
    COMPUTE(buf); \
    asm volatile("s_waitcnt lgkmcnt(0)" ::: "memory"); \
    __builtin_amdgcn_s_barrier(); \
    if (DO_STAGE) STAGE(buf, (kt) + 3); \
} while (0)

    STAGE(0, 0); STAGE(1, 1); STAGE(2, 2);
    #pragma unroll 1
    for (int base = 0; base < 27; base += 3) {
        KSTEP(0, base + 0, 8, 1);
        KSTEP(1, base + 1, 8, 1);
        KSTEP(2, base + 2, 8, 1);
    }
    KSTEP(0, 27, 8, 1);
    KSTEP(1, 28, 8, 1);
    KSTEP(2, 29, 8, 0);
    KSTEP(0, 30, 4, 0);
    KSTEP(1, 31, 0, 0);

    // epilogue: bias + tanh + bf16 store
    #pragma unroll
    for (int m = 0; m < 2; m++) {
        #pragma unroll
        for (int n = 0; n < 4; n++) {
            int col = n0 + wc * 64 + n * 16 + lr;
            float bias = b1[col];
            #pragma unroll
            for (int j = 0; j < 4; j++) {
                int row = m0 + wr * 32 + m * 16 + lg * 4 + j;
                float v = tanhf(acc[m][n][j] + bias);
                ts[(size_t)row * 512 + col] = f2bf(v);
            }
        }
    }
#undef STAGE
#undef COMPUTE
#undef KSTEP
}

// ---------------------------------------------------------------------------
// FUSED gemm2 + softmax + sigmoid + recurrence. One block = one batch.
// Band transposed in LDS (jwT_s[c][k], pad 65). Recurrence (wave 0):
// band column in 16 NAMED f32x4 registers B0..B15 (no indexable array ->
// cannot be demoted to scratch; rule #20), __launch_bounds__(256,1) lifts
// the VGPR budget so the allocator keeps them resident.
// Per iter: 1 ds_write + 16 uniform-addr ds_read_b128 broadcasts + 64 FMA.
// ---------------------------------------------------------------------------
__global__ __launch_bounds__(256, 1) void gemm2_recur_kernel(
    const u16* __restrict__ ts, const u16* __restrict__ W23B,
    const float* __restrict__ b2, const float* __restrict__ b3,
    const float* __restrict__ em, const int* __restrict__ slen,
    float* __restrict__ out)
{
    __shared__ float jwT_s[64][65];   // [c][k] = M[k][c]
    __shared__ float em_s[128][65];
    __shared__ float p0_s[64];
    __shared__ f32x4 a_bc4[16];       // 16B-aligned broadcast buffer
    const int b = blockIdx.x;
    const int tid = threadIdx.x;
    const int w = tid >> 6, lane = tid & 63;
    const int lr = lane & 15, lg = lane >> 4;
    const int r0 = b * 64 + w * 16;

    // stage emission (independent of the GEMM; overlaps it)
    {
        const float4* eg = (const float4*)(em + (size_t)b * 8192);
        #pragma unroll
        for (int q = 0; q < 8; ++q) {
            int i4 = tid + q * 256;
            float4 v = eg[i4];
            int base = i4 * 4; int n = base >> 6; int ii = base & 63;
            em_s[n][ii] = v.x; em_s[n][ii + 1] = v.y; em_s[n][ii + 2] = v.z; em_s[n][ii + 3] = v.w;
        }
    }

    f32x4 acc[9];
    #pragma unroll
    for (int ct = 0; ct < 9; ct++) { f32x4 z = {0.f,0.f,0.f,0.f}; acc[ct] = z; }

    #pragma unroll 4
    for (int kk = 0; kk < 16; ++kk) {
        bf16x8 a = *(const bf16x8*)(ts + (size_t)(r0 + lr) * 512 + kk * 32 + lg * 8);
        #pragma unroll
        for (int ct = 0; ct < 9; ct++) {
            bf16x8 bv = *(const bf16x8*)(W23B + ((size_t)(kk * 9 + ct) * 64 + lane) * 8);
            acc[ct] = __builtin_amdgcn_mfma_f32_16x16x32_bf16(a, bv, acc[ct], 0, 0, 0);
        }
    }

    float b3v = b3[0];
    #pragma unroll
    for (int j = 0; j < 4; j++) {
        int rloc = w * 16 + lg * 4 + j;   // row within batch (0..63)
        float v[9];
        float mx = -1e30f;
        #pragma unroll
        for (int ct = 0; ct < 9; ct++) {
            int col = ct * 16 + lr;
            if (col < 129) { float x = acc[ct][j] + b2[col]; v[ct] = x; mx = fmaxf(mx, x); }
            else v[ct] = -1e30f;
        }
        #pragma unroll
        for (int o = 1; o < 16; o <<= 1) mx = fmaxf(mx, __shfl_xor(mx, o));
        float sum = 0.f;
        #pragma unroll
        for (int ct = 0; ct < 9; ct++) {
            int col = ct * 16 + lr;
            if (col < 129) { float e = expf(v[ct] - mx); v[ct] = e; sum += e; }
        }
        #pragma unroll
        for (int o = 1; o < 16; o <<= 1) sum += __shfl_xor(sum, o);
        float inv = 1.0f / sum;
        #pragma unroll
        for (int ct = 0; ct < 9; ct++) {
            int col = ct * 16 + lr;
            int cc = col - 64 + rloc;
            if (col < 129 && cc >= 0 && cc < 64)
                jwT_s[cc][rloc] = v[ct] * inv;   // transposed band write
        }
        if (lr == 1) {  // col 129 = p0 logit
            float pv = acc[8][j] + b3v;
            p0_s[rloc] = 1.0f / (1.0f + expf(-pv));
        }
    }
    __syncthreads();
    if (tid >= 64) return;

    // ---- recurrence, wave 0 only ----
    const int c = tid;
    // band column -> 16 NAMED f32x4 registers (64 VGPRs, cannot spill as array)
    f32x4 B0  = *(const f32x4*)&jwT_s[c][0];
    f32x4 B1  = *(const f32x4*)&jwT_s[c][4];
    f32x4 B2  = *(const f32x4*)&jwT_s[c][8];
    f32x4 B3  = *(const f32x4*)&jwT_s[c][12];
    f32x4 B4  = *(const f32x4*)&jwT_s[c][16];
    f32x4 B5  = *(const f32x4*)&jwT_s[c][20];
    f32x4 B6  = *(const f32x4*)&jwT_s[c][24];
    f32x4 B7  = *(const f32x4*)&jwT_s[c][28];
    f32x4 B8  = *(const f32x4*)&jwT_s[c][32];
    f32x4 B9  = *(const f32x4*)&jwT_s[c][36];
    f32x4 B10 = *(const f32x4*)&jwT_s[c][40];
    f32x4 B11 = *(const f32x4*)&jwT_s[c][44];
    f32x4 B12 = *(const f32x4*)&jwT_s[c][48];
    f32x4 B13 = *(const f32x4*)&jwT_s[c][52];
    f32x4 B14 = *(const f32x4*)&jwT_s[c][56];
    f32x4 B15 = *(const f32x4*)&jwT_s[c][60];
    const float p0r = p0_s[c];
    const int idx = slen[b] - 1;

    float ut = em_s[c][0] + em_s[c + 64][0];   // atil_0
    float Lacc = 0.f;   // sum of log2(r) at rescale points

#define ACC4(Q, BV) do { \
    f32x4 av_ = a_bc4[Q]; \
    s0 = fmaf(av_[0], (BV)[0], s0); \
    s1 = fmaf(av_[1], (BV)[1], s1); \
    s2 = fmaf(av_[2], (BV)[2], s2); \
    s3 = fmaf(av_[3], (BV)[3], s3); \
} while (0)

    #pragma unroll 1
    for (int i = 1; i <= idx; ++i) {
        ((float*)a_bc4)[c] = ut;      // per-lane ds_write
        float aloc = ut;              // diagonal-term source
        asm volatile("s_waitcnt lgkmcnt(0)" ::: "memory");
        float s0 = 0.f, s1 = 0.f, s2 = 0.f, s3 = 0.f;
        ACC4(0, B0);  ACC4(1, B1);  ACC4(2, B2);  ACC4(3, B3);
        ACC4(4, B4);  ACC4(5, B5);  ACC4(6, B6);  ACC4(7, B7);
        ACC4(8, B8);  ACC4(9, B9);  ACC4(10, B10); ACC4(11, B11);
        ACC4(12, B12); ACC4(13, B13); ACC4(14, B14); ACC4(15, B15);
        ut = ((s0 + s1) + (s2 + s3)) * em_s[c][i] + aloc * p0r * em_s[c + 64][i];
        if (((i & 3) == 0) || (i == idx)) {
            float r = ut;
            #pragma unroll
            for (int o = 1; o < 64; o <<= 1) r += __shfl_xor(r, o);
            Lacc += __log2f(r);
            ut *= __builtin_amdgcn_rcpf(r);
        }
    }
#undef ACC4
    if (c == 0) out[b] = 1.0f + 0.6931471805599453f * (Lacc + 7.0f * (float)idx);
}

extern "C" void kernel_launch(void* const* d_in, const int* in_sizes, int n_in,
                              void* d_out, int out_size, void* d_ws, size_t ws_size,
                              hipStream_t stream)
{
    const float* Y   = (const float*)d_in[0];
    const float* em  = (const float*)d_in[1];
    const int*   sl  = (const int*)d_in[2];
    const float* W1  = (const float*)d_in[3];
    const float* b1  = (const float*)d_in[4];
    const float* W2  = (const float*)d_in[5];
    const float* b2  = (const float*)d_in[6];
    const float* W3  = (const float*)d_in[7];
    const float* b3  = (const float*)d_in[8];
    float* out = (float*)d_out;
    char* ws = (char*)d_ws;

    __bf16* W1T  = (__bf16*)(ws + OFF_W1T);
    __bf16* W23B = (__bf16*)(ws + OFF_W23B);
    u16*    ts   = (u16*)(ws + OFF_TS);

    prep_kernel<<<164, 256, 0, stream>>>(W1, W2, W3, W1T, W23B);
    dim3 g1(128, 4);
    gemm1_kernel<<<g1, 256, 0, stream>>>(Y, W1T, b1, ts);
    gemm2_recur_kernel<<<128, 256, 0, stream>>>(ts, (const u16*)W23B, b2, b3, em, sl, out);
}